// Round 12
// baseline (319.830 us; speedup 1.0000x reference)
//
#include <hip/hip_runtime.h>

typedef unsigned short u16;
typedef __bf16 bf16x8 __attribute__((ext_vector_type(8)));
typedef float f32x4 __attribute__((ext_vector_type(4)));

#define DEV static __device__ __forceinline__

#if __has_builtin(__builtin_amdgcn_exp2f)
#define EXP2(x) __builtin_amdgcn_exp2f(x)
#else
#define EXP2(x) exp2f(x)
#endif

DEV u16 f2bf(float f) {
    union { float f; unsigned u; } a; a.f = f;
    unsigned r = a.u + 0x7fffu + ((a.u >> 16) & 1u);
    return (u16)(r >> 16);
}

DEV f32x4 fzero() { f32x4 z; z[0]=0.f; z[1]=0.f; z[2]=0.f; z[3]=0.f; return z; }

DEV bf16x8 load8(const u16* p) {
    uint4 u = *(const uint4*)p;
    union { uint4 u; bf16x8 b; } c; c.u = u; return c.b;
}

DEV f32x4 mfma16(bf16x8 a, bf16x8 b, f32x4 c) {
    return __builtin_amdgcn_mfma_f32_16x16x32_bf16(a, b, c, 0, 0, 0);
}

typedef __attribute__((address_space(1))) void as1_void;
typedef __attribute__((address_space(3))) void as3_void;

DEV void async16(const u16* g, u16* lds) {
    __builtin_amdgcn_global_load_lds((as1_void*)g, (as3_void*)lds, 16, 0, 0);
}

// 0.125 * log2(e): fused scale so attn can use exp2 directly
#define QSCALE 0.18033688011112042f

// ---------------- fused weight prep: all transposes + bias concat, ONE dispatch ----------
__global__ __launch_bounds__(256)
void prep(const float* __restrict__ wq, const float* __restrict__ wk,
          const float* __restrict__ wv, const float* __restrict__ wo,
          const float* __restrict__ w1, const float* __restrict__ w2,
          const float* __restrict__ bq, const float* __restrict__ bk,
          const float* __restrict__ bv, u16* __restrict__ wT,
          float* __restrict__ bqkv) {
    const int bid = blockIdx.x;
    if (bid >= 6144) {                      // bias concat: 12 blocks x 256
        int i = bid - 6144;
        int l = i / 6, idx = (i % 6) * 256 + threadIdx.x;
        float v = idx < 512 ? bq[l * 512 + idx]
                : idx < 1024 ? bk[l * 512 + idx - 512]
                : bv[l * 512 + idx - 1024];
        bqkv[l * 1536 + idx] = v;
        return;
    }
    const int l = bid / 3072, t = bid % 3072;
    u16* base = wT + (size_t)l * 3145728;
    const size_t o512 = (size_t)l * 262144, o1m = (size_t)l * 1048576;
    const float* src; u16* dst; int K, N, tn, tk;
    if (t < 1024) {                         // wq,wk,wv,wo: 256 tiles each
        int m = t >> 8, r = t & 255;
        src = m == 0 ? wq + o512 : m == 1 ? wk + o512 : m == 2 ? wv + o512 : wo + o512;
        dst = base + (size_t)m * 262144;
        K = 512; N = 512; tn = r & 15; tk = r >> 4;
    } else if (t < 2048) {                  // w1 (512x2048)
        int r = t - 1024;
        src = w1 + o1m; dst = base + 1048576;
        K = 512; N = 2048; tn = r & 63; tk = r >> 6;
    } else {                                // w2 (2048x512)
        int r = t - 2048;
        src = w2 + o1m; dst = base + 2097152;
        K = 2048; N = 512; tn = r & 15; tk = r >> 4;
    }
    __shared__ float tile[32][33];
    const int tx = threadIdx.x & 31, ty = threadIdx.x >> 5;
    const int n0 = tn * 32, k0 = tk * 32;
#pragma unroll
    for (int i = 0; i < 4; i++)
        tile[ty + i * 8][tx] = src[(size_t)(k0 + ty + i * 8) * N + n0 + tx];
    __syncthreads();
#pragma unroll
    for (int i = 0; i < 4; i++)
        dst[(size_t)(n0 + ty + i * 8) * K + k0 + tx] = f2bf(tile[tx][ty + i * 8]);
}

// ---------------- LayerNorm ----------------
DEV void ln_body(const float* xr, const float* g, const float* bb, u16* orow) {
    const int t = threadIdx.x;
    float v0 = xr[t], v1 = xr[t + 256];
    float s = v0 + v1, s2 = v0 * v0 + v1 * v1;
#pragma unroll
    for (int off = 32; off > 0; off >>= 1) {
        s  += __shfl_down(s,  off);
        s2 += __shfl_down(s2, off);
    }
    __shared__ float red[8];
    const int w = t >> 6, ln = t & 63;
    if (ln == 0) { red[w] = s; red[4 + w] = s2; }
    __syncthreads();
    s  = red[0] + red[1] + red[2] + red[3];
    s2 = red[4] + red[5] + red[6] + red[7];
    float mean = s * (1.f / 512.f);
    float var  = s2 * (1.f / 512.f) - mean * mean;
    float rstd = rsqrtf(var + 1e-5f);
    orow[t]       = f2bf((v0 - mean) * rstd * g[t]       + bb[t]);
    orow[t + 256] = f2bf((v1 - mean) * rstd * g[t + 256] + bb[t + 256]);
}

__global__ __launch_bounds__(256)
void ln_k(const float* __restrict__ x, const float* __restrict__ g,
          const float* __restrict__ bb, u16* __restrict__ o) {
    const int row = blockIdx.x;
    ln_body(x + (size_t)row * 512, g, bb, o + (size_t)row * 512);
}

__global__ __launch_bounds__(256)
void lnd_k(const float* __restrict__ x0, u16* __restrict__ o0,
           const float* __restrict__ x1, u16* __restrict__ o1,
           const float* __restrict__ g, const float* __restrict__ bb) {
    const int row = blockIdx.x;
    const float* x = blockIdx.y ? x1 : x0;
    u16* o = blockIdx.y ? o1 : o0;
    ln_body(x + (size_t)row * 512, g, bb, o + (size_t)row * 512);
}

// ---------------- GEMM: A (M,K) bf16 @ Bt (N,K) bf16 + bias -> out ----------------
// Grid: blockIdx.x = m-tile (FAST), blockIdx.y = n-tile (outer) — measured best (R9/R11).
// BK=32: linear LDS rows. BK=64: 128B rows, XOR swizzle both sides (rule #21).
// EPI 0: bf16 = acc+bias ; 1: bf16 relu ; 2: f32 = acc+bias+res
template<int BN, int BK, int EPI>
__global__ __launch_bounds__(256, 3)
void gemm_k(const u16* __restrict__ A, const u16* __restrict__ Bt,
            const float* __restrict__ bias, const float* __restrict__ res,
            void* __restrict__ outp, int M, int N, int K) {
    __shared__ u16 As[2][128 * BK];
    __shared__ u16 Bs[2][BN * BK];
    const int tid = threadIdx.x, w = tid >> 6, ln = tid & 63;
    const int m0 = blockIdx.x * 128, n0 = blockIdx.y * BN;
    const int wr = (w >> 1) * 64, wc = (w & 1) * (BN / 2);
    const int l15 = ln & 15, l4 = ln >> 4;
    constexpr int NI = BN / 32;

    f32x4 acc[4][NI];
#pragma unroll
    for (int mi = 0; mi < 4; mi++)
#pragma unroll
        for (int ni = 0; ni < NI; ni++) acc[mi][ni] = fzero();

    auto stage = [&](int buf, int k0) {
        if constexpr (BK == 32) {
#pragma unroll
            for (int i = 0; i < 2; i++) {               // A: 8 chunks of 16 rows
                int chunk = i * 4 + w;
                int r = chunk * 16 + (ln >> 2);
                async16(A + (size_t)(m0 + r) * K + k0 + (ln & 3) * 8, &As[buf][chunk * 512]);
            }
#pragma unroll
            for (int i = 0; i < BN / 64; i++) {
                int chunk = i * 4 + w;
                int r = chunk * 16 + (ln >> 2);
                async16(Bt + (size_t)(n0 + r) * K + k0 + (ln & 3) * 8, &Bs[buf][chunk * 512]);
            }
        } else {                                        // BK == 64, swizzled
            const int srow = ln >> 3;
            const int scol = ((ln & 7) ^ srow) * 8;
#pragma unroll
            for (int i = 0; i < 4; i++) {               // A: 16 chunks of 8 rows
                int chunk = i * 4 + w;
                int r = chunk * 8 + srow;
                async16(A + (size_t)(m0 + r) * K + k0 + scol, &As[buf][chunk * 512]);
            }
#pragma unroll
            for (int i = 0; i < BN / 32; i++) {         // B: BN/8 chunks of 8 rows
                int chunk = i * 4 + w;
                int r = chunk * 8 + srow;
                async16(Bt + (size_t)(n0 + r) * K + k0 + scol, &Bs[buf][chunk * 512]);
            }
        }
    };

    stage(0, 0);
    __syncthreads();
    const int nk = K / BK;
    for (int kt = 0; kt < nk; ++kt) {
        const int cur = kt & 1;
        if (kt + 1 < nk) stage(cur ^ 1, (kt + 1) * BK);
        if constexpr (BK == 32) {
            bf16x8 a[4], b[NI];
#pragma unroll
            for (int mi = 0; mi < 4; mi++)
                a[mi] = load8(&As[cur][(wr + mi * 16 + l15) * 32 + l4 * 8]);
#pragma unroll
            for (int ni = 0; ni < NI; ni++)
                b[ni] = load8(&Bs[cur][(wc + ni * 16 + l15) * 32 + l4 * 8]);
#pragma unroll
            for (int mi = 0; mi < 4; mi++)
#pragma unroll
                for (int ni = 0; ni < NI; ni++)
                    acc[mi][ni] = mfma16(a[mi], b[ni], acc[mi][ni]);
        } else {
            const int swl = (l15 & 7) << 4;
#pragma unroll
            for (int ks = 0; ks < 2; ks++) {
                bf16x8 a[4], b[NI];
#pragma unroll
                for (int mi = 0; mi < 4; mi++) {
                    const char* ba = (const char*)&As[cur][(wr + mi * 16 + l15) * 64];
                    a[mi] = load8((const u16*)(ba + ((ks * 64 + l4 * 16) ^ swl)));
                }
#pragma unroll
                for (int ni = 0; ni < NI; ni++) {
                    const char* bb2 = (const char*)&Bs[cur][(wc + ni * 16 + l15) * 64];
                    b[ni] = load8((const u16*)(bb2 + ((ks * 64 + l4 * 16) ^ swl)));
                }
#pragma unroll
                for (int mi = 0; mi < 4; mi++)
#pragma unroll
                    for (int ni = 0; ni < NI; ni++)
                        acc[mi][ni] = mfma16(a[mi], b[ni], acc[mi][ni]);
            }
        }
        __syncthreads();
    }

#pragma unroll
    for (int mi = 0; mi < 4; mi++)
#pragma unroll
        for (int ni = 0; ni < NI; ni++) {
            int row0 = m0 + wr + mi * 16 + l4 * 4;
            int col  = n0 + wc + ni * 16 + l15;
            float bv = bias[col];
#pragma unroll
            for (int j = 0; j < 4; j++) {
                float v = acc[mi][ni][j] + bv;
                size_t off = (size_t)(row0 + j) * N + col;
                if constexpr (EPI == 2) ((float*)outp)[off] = v + res[off];
                else if constexpr (EPI == 1) ((u16*)outp)[off] = f2bf(v > 0.f ? v : 0.f);
                else ((u16*)outp)[off] = f2bf(v);
            }
        }
}

// ---------------- merged QKV GEMM (N=1536), V written transposed ----------------
// grid (64, 12): m fast (R9 order)
__global__ __launch_bounds__(256, 3)
void gemm_qkv(const u16* __restrict__ A1, const u16* __restrict__ A2,
              const u16* __restrict__ Bt, const float* __restrict__ bias,
              u16* __restrict__ qkB, u16* __restrict__ vTp) {
    constexpr int K = 512;
    __shared__ u16 As[2][128 * 32];
    __shared__ u16 Bs[2][128 * 32];
    const int tid = threadIdx.x, w = tid >> 6, ln = tid & 63;
    const int m0 = blockIdx.x * 128, n0 = blockIdx.y * 128;
    const int wr = (w >> 1) * 64, wc = (w & 1) * 64;
    const int l15 = ln & 15, l4 = ln >> 4;
    const u16* A = (n0 >= 512) ? A2 : A1;

    f32x4 acc[4][4];
#pragma unroll
    for (int mi = 0; mi < 4; mi++)
#pragma unroll
        for (int ni = 0; ni < 4; ni++) acc[mi][ni] = fzero();

    auto stage = [&](int buf, int k0) {
#pragma unroll
        for (int i = 0; i < 2; i++) {
            int chunk = i * 4 + w;
            int r = chunk * 16 + (ln >> 2);
            async16(A + (size_t)(m0 + r) * K + k0 + (ln & 3) * 8, &As[buf][chunk * 512]);
            async16(Bt + (size_t)(n0 + r) * K + k0 + (ln & 3) * 8, &Bs[buf][chunk * 512]);
        }
    };

    stage(0, 0);
    __syncthreads();
    for (int kt = 0; kt < 16; ++kt) {
        const int cur = kt & 1;
        if (kt + 1 < 16) stage(cur ^ 1, (kt + 1) * 32);
        bf16x8 a[4], b[4];
#pragma unroll
        for (int mi = 0; mi < 4; mi++)
            a[mi] = load8(&As[cur][(wr + mi * 16 + l15) * 32 + l4 * 8]);
#pragma unroll
        for (int ni = 0; ni < 4; ni++)
            b[ni] = load8(&Bs[cur][(wc + ni * 16 + l15) * 32 + l4 * 8]);
#pragma unroll
        for (int mi = 0; mi < 4; mi++)
#pragma unroll
            for (int ni = 0; ni < 4; ni++)
                acc[mi][ni] = mfma16(a[mi], b[ni], acc[mi][ni]);
        __syncthreads();
    }

    if (n0 < 1024) {
        const float scale = (n0 < 512) ? QSCALE : 1.f;   // Q prescaled for exp2 softmax
#pragma unroll
        for (int mi = 0; mi < 4; mi++)
#pragma unroll
            for (int ni = 0; ni < 4; ni++) {
                int row0 = m0 + wr + mi * 16 + l4 * 4;
                int col  = n0 + wc + ni * 16 + l15;
                float bv = bias[col];
#pragma unroll
                for (int j = 0; j < 4; j++)
                    qkB[(size_t)(row0 + j) * 1024 + col] = f2bf((acc[mi][ni][j] + bv) * scale);
            }
    } else {
#pragma unroll
        for (int mi = 0; mi < 4; mi++)
#pragma unroll
            for (int ni = 0; ni < 4; ni++) {
                int row0 = m0 + wr + mi * 16 + l4 * 4;
                int col  = n0 + wc + ni * 16 + l15;
                float bv = bias[col];
                int c = col - 1024;
                int bh = (row0 >> 11) * 8 + (c >> 6);
                ushort4 pk;
                pk.x = f2bf(acc[mi][ni][0] + bv);
                pk.y = f2bf(acc[mi][ni][1] + bv);
                pk.z = f2bf(acc[mi][ni][2] + bv);
                pk.w = f2bf(acc[mi][ni][3] + bv);
                *(ushort4*)(vTp + (size_t)bh * 131072 + (size_t)(c & 63) * 2048 + (row0 & 2047)) = pk;
            }
    }
}

// ---------------- flash attention v6: swapped QK^T, exp2, perm-pack, setprio ----------
__global__ __launch_bounds__(256, 3)
void attn_k(const u16* __restrict__ qh, int qstr, const u16* __restrict__ kh, int kstr,
            const u16* __restrict__ vT, u16* __restrict__ o) {
    __shared__ u16 Kt[2][4096];   // [kk][hd] swizzled rows, 64 x 128B
    __shared__ u16 Vt[2][4096];   // [hd][kk] swizzled rows, 64 x 128B
    __shared__ u16 Pl[4][2048];   // per-wave [q][kk], 32 x 128B, swizzled rows
    const int tid = threadIdx.x, w = tid >> 6, ln = tid & 63;
    const int orig = blockIdx.y * 16 + blockIdx.x;   // nwg=512, cpx=64
    const int swz = (orig & 7) * 64 + (orig >> 3);
    const int bx = swz & 15, by = swz >> 4;
    const int b = by >> 3, h = by & 7;
    const int q0 = bx * 128;
    const size_t bS = (size_t)b * 2048;
    const int h64 = h * 64;
    const int l15 = ln & 15, l4 = ln >> 4;

    const int srow = ln >> 3;
    const int scol = ((ln & 7) ^ srow) * 8;

    const u16* qp = qh + (bS + q0 + w * 32 + l15) * qstr + h64;
    bf16x8 qa[2][2];
    qa[0][0] = load8(qp + l4 * 8);
    qa[0][1] = load8(qp + 32 + l4 * 8);
    qa[1][0] = load8(qp + 16 * qstr + l4 * 8);
    qa[1][1] = load8(qp + 16 * qstr + 32 + l4 * 8);

    const u16* kbase = kh + bS * kstr + h64;
    const u16* vbase = vT + (size_t)(b * 8 + h) * 131072;

    auto stage = [&](int buf, int sk) {
#pragma unroll
        for (int i = 0; i < 2; i++) {
            int chunk = i * 4 + w;
            int row = chunk * 8 + srow;
            async16(kbase + (size_t)(sk + row) * kstr + scol, &Kt[buf][chunk * 512]);
            async16(vbase + (size_t)row * 2048 + sk + scol, &Vt[buf][chunk * 512]);
        }
    };

    float l_acc[2];
    f32x4 oacc[2][4];
#pragma unroll
    for (int mf = 0; mf < 2; mf++) {
        l_acc[mf] = 0.f;
#pragma unroll
        for (int j = 0; j < 4; j++) oacc[mf][j] = fzero();
    }

    const int swl = (l15 & 7) << 4;

    stage(0, 0);
    for (int t = 0; t < 32; ++t) {
        const int cur = t & 1;
        __syncthreads();
        if (t < 31) stage(cur ^ 1, (t + 1) * 64);

        const char* KtC = (const char*)Kt[cur];
        const char* VtC = (const char*)Vt[cur];

        // S^T = mfma(K, Q): s[mf][ni] -> lane: q = mf*16+l15, kk = ni*16+l4*4+j
        f32x4 s[2][4];
        __builtin_amdgcn_s_setprio(1);
#pragma unroll
        for (int ni = 0; ni < 4; ni++) {
            const char* kr = KtC + (ni * 16 + l15) * 128;
            bf16x8 kb0 = load8((const u16*)(kr + ((l4 * 16) ^ swl)));
            bf16x8 kb1 = load8((const u16*)(kr + ((64 + l4 * 16) ^ swl)));
            s[0][ni] = mfma16(kb0, qa[0][0], fzero());
            s[0][ni] = mfma16(kb1, qa[0][1], s[0][ni]);
            s[1][ni] = mfma16(kb0, qa[1][0], fzero());
            s[1][ni] = mfma16(kb1, qa[1][1], s[1][ni]);
        }
        __builtin_amdgcn_s_setprio(0);

        // P = 2^s (Q prescaled by 0.125*log2e); truncate-pack via v_perm; raw l-sum
        char* Pw = (char*)Pl[w];
#pragma unroll
        for (int mf = 0; mf < 2; mf++) {
            const int qrow = mf * 16 + l15;
            char* Pr = Pw + qrow * 128;
            const int qsw = (qrow & 7) << 4;
#pragma unroll
            for (int jj = 0; jj < 2; jj++)
#pragma unroll
                for (int ni = 0; ni < 4; ni++) {
                    const int boff = ni * 32 + l4 * 8;
                    float p0 = EXP2(s[mf][ni][jj * 2]);
                    float p1 = EXP2(s[mf][ni][jj * 2 + 1]);
                    union { float f; unsigned u; } c0, c1;
                    c0.f = p0; c1.f = p1;
                    l_acc[mf] += p0 + p1;
                    *(unsigned*)(Pr + ((boff + jj * 4) ^ qsw)) =
                        __builtin_amdgcn_perm(c1.u, c0.u, 0x07060302u);
                }
        }

        // PV: oacc[mf][hd4] += P(32x64) @ V^T rows
        bf16x8 pa[2][2];
#pragma unroll
        for (int mf = 0; mf < 2; mf++) {
            pa[mf][0] = load8((const u16*)(Pw + (mf * 16 + l15) * 128 + ((l4 * 16) ^ swl)));
            pa[mf][1] = load8((const u16*)(Pw + (mf * 16 + l15) * 128 + ((64 + l4 * 16) ^ swl)));
        }
        __builtin_amdgcn_s_setprio(1);
#pragma unroll
        for (int hd4 = 0; hd4 < 4; hd4++) {
            const char* vr = VtC + (hd4 * 16 + l15) * 128;
            bf16x8 vb0 = load8((const u16*)(vr + ((l4 * 16) ^ swl)));
            bf16x8 vb1 = load8((const u16*)(vr + ((64 + l4 * 16) ^ swl)));
            oacc[0][hd4] = mfma16(pa[0][0], vb0, oacc[0][hd4]);
            oacc[0][hd4] = mfma16(pa[0][1], vb1, oacc[0][hd4]);
            oacc[1][hd4] = mfma16(pa[1][0], vb0, oacc[1][hd4]);
            oacc[1][hd4] = mfma16(pa[1][1], vb1, oacc[1][hd4]);
        }
        __builtin_amdgcn_s_setprio(0);
    }

    // reduce l across the 4 l4 groups, redistribute to O-write layout
    float rlj[2][4];
#pragma unroll
    for (int mf = 0; mf < 2; mf++) {
        l_acc[mf] += __shfl_xor(l_acc[mf], 16);
        l_acc[mf] += __shfl_xor(l_acc[mf], 32);
        float inv = 1.f / l_acc[mf];
#pragma unroll
        for (int j = 0; j < 4; j++)
            rlj[mf][j] = __shfl(inv, (ln & 48) | (l4 * 4 + j));
    }

#pragma unroll
    for (int mf = 0; mf < 2; mf++)
#pragma unroll
        for (int hd4 = 0; hd4 < 4; hd4++)
#pragma unroll
            for (int j = 0; j < 4; j++) {
                float v = oacc[mf][hd4][j] * rlj[mf][j];
                size_t row = bS + q0 + w * 32 + mf * 16 + l4 * 4 + j;
                o[row * 512 + h64 + hd4 * 16 + l15] = f2bf(v);
            }
}

// ---------------- driver ----------------
extern "C" void kernel_launch(void* const* d_in, const int* in_sizes, int n_in,
                              void* d_out, int out_size, void* d_ws, size_t ws_size,
                              hipStream_t stream) {
    const float* q    = (const float*)d_in[0];
    const float* ln1g = (const float*)d_in[1];
    const float* ln1b = (const float*)d_in[2];
    const float* wq   = (const float*)d_in[3];
    const float* bq   = (const float*)d_in[4];
    const float* wk   = (const float*)d_in[5];
    const float* bk   = (const float*)d_in[6];
    const float* wv   = (const float*)d_in[7];
    const float* bv   = (const float*)d_in[8];
    const float* wo   = (const float*)d_in[9];
    const float* bo   = (const float*)d_in[10];
    const float* ln2g = (const float*)d_in[11];
    const float* ln2b = (const float*)d_in[12];
    const float* w1   = (const float*)d_in[13];
    const float* b1   = (const float*)d_in[14];
    const float* w2   = (const float*)d_in[15];
    const float* b2   = (const float*)d_in[16];

    char* ws = (char*)d_ws;
    size_t off = 0;
    auto take = [&](size_t bytes) -> char* {
        char* p = ws + off; off += (bytes + 255) & ~(size_t)255; return p;
    };
    u16*   wT   = (u16*)take(6291456ull * 2);    // transposed bf16 weights
    float* bqkv = (float*)take(2 * 1536 * 4);    // per-layer concat(bq,bk,bv)
    float* xA   = (float*)take(4194304ull * 4);  // f32 residual stream A
    float* xB   = (float*)take(4194304ull * 4);  // f32 residual stream B
    u16*   qn   = (u16*)take(4194304ull * 2);    // LN(x); reused as attn output
    u16*   kn   = (u16*)take(4194304ull * 2);    // LN(q); reused as LN2 output
    u16*   qkB  = (u16*)take(8388608ull * 2);    // merged Q|K proj (8192 x 1024)
    u16*   hbuf = (u16*)take(16777216ull * 2);   // FFN hidden bf16
    u16*   vTb  = hbuf;                          // alias: vT used only pre-FFN
    (void)ws_size; (void)in_sizes; (void)n_in; (void)out_size;

    prep<<<6156, 256, 0, stream>>>(wq, wk, wv, wo, w1, w2, bq, bk, bv, wT, bqkv);

    const float* xcur = q;
    for (int l = 0; l < 2; l++) {
        u16* base = wT + (size_t)l * 3145728;
        if (l == 0) {
            ln_k<<<8192, 256, 0, stream>>>(q, ln1g, ln1b, qn);       // x==q: one LN
        } else {
            lnd_k<<<dim3(8192, 2), 256, 0, stream>>>(xcur, qn, q, kn,
                                                     ln1g + 512, ln1b + 512);
        }
        const u16* A2 = (l == 0) ? qn : kn;
        gemm_qkv<<<dim3(64, 12), 256, 0, stream>>>(qn, A2, base, bqkv + l * 1536, qkB, vTb);
        attn_k<<<dim3(16, 32), 256, 0, stream>>>(qkB, 1024, qkB + 512, 1024, vTb, qn);
        gemm_k<64, 64, 2><<<dim3(64, 8), 256, 0, stream>>>(qn, base + 786432, bo + l * 512, xcur, xA, 8192, 512, 512);
        ln_k<<<8192, 256, 0, stream>>>(xA, ln2g + l * 512, ln2b + l * 512, kn);
        gemm_k<64, 64, 1><<<dim3(64, 32), 256, 0, stream>>>(kn, base + 1048576, b1 + l * 2048, nullptr, hbuf, 8192, 2048, 512);
        float* xout = (l == 1) ? (float*)d_out : xB;
        gemm_k<64, 64, 2><<<dim3(64, 8), 256, 0, stream>>>(hbuf, base + 2097152, b2 + l * 512, xA, xout, 8192, 512, 2048);
        xcur = xout;
    }
}

// Round 13
// 316.607 us; speedup vs baseline: 1.0102x; 1.0102x over previous
//
#include <hip/hip_runtime.h>

typedef unsigned short u16;
typedef __bf16 bf16x8 __attribute__((ext_vector_type(8)));
typedef float f32x4 __attribute__((ext_vector_type(4)));

#define DEV static __device__ __forceinline__

#if __has_builtin(__builtin_amdgcn_exp2f)
#define EXP2(x) __builtin_amdgcn_exp2f(x)
#else
#define EXP2(x) exp2f(x)
#endif

DEV u16 f2bf(float f) {
    union { float f; unsigned u; } a; a.f = f;
    unsigned r = a.u + 0x7fffu + ((a.u >> 16) & 1u);
    return (u16)(r >> 16);
}

DEV f32x4 fzero() { f32x4 z; z[0]=0.f; z[1]=0.f; z[2]=0.f; z[3]=0.f; return z; }

DEV bf16x8 load8(const u16* p) {
    uint4 u = *(const uint4*)p;
    union { uint4 u; bf16x8 b; } c; c.u = u; return c.b;
}

DEV f32x4 mfma16(bf16x8 a, bf16x8 b, f32x4 c) {
    return __builtin_amdgcn_mfma_f32_16x16x32_bf16(a, b, c, 0, 0, 0);
}

typedef __attribute__((address_space(1))) void as1_void;
typedef __attribute__((address_space(3))) void as3_void;

DEV void async16(const u16* g, u16* lds) {
    __builtin_amdgcn_global_load_lds((as1_void*)g, (as3_void*)lds, 16, 0, 0);
}

// 0.125 * log2(e): fused scale so attn can use exp2 directly
#define QSCALE 0.18033688011112042f

// ---------------- fused weight prep: all transposes + bias concat, ONE dispatch ----------
__global__ __launch_bounds__(256)
void prep(const float* __restrict__ wq, const float* __restrict__ wk,
          const float* __restrict__ wv, const float* __restrict__ wo,
          const float* __restrict__ w1, const float* __restrict__ w2,
          const float* __restrict__ bq, const float* __restrict__ bk,
          const float* __restrict__ bv, u16* __restrict__ wT,
          float* __restrict__ bqkv) {
    const int bid = blockIdx.x;
    if (bid >= 6144) {                      // bias concat: 12 blocks x 256
        int i = bid - 6144;
        int l = i / 6, idx = (i % 6) * 256 + threadIdx.x;
        float v = idx < 512 ? bq[l * 512 + idx]
                : idx < 1024 ? bk[l * 512 + idx - 512]
                : bv[l * 512 + idx - 1024];
        bqkv[l * 1536 + idx] = v;
        return;
    }
    const int l = bid / 3072, t = bid % 3072;
    u16* base = wT + (size_t)l * 3145728;
    const size_t o512 = (size_t)l * 262144, o1m = (size_t)l * 1048576;
    const float* src; u16* dst; int K, N, tn, tk;
    if (t < 1024) {                         // wq,wk,wv,wo: 256 tiles each
        int m = t >> 8, r = t & 255;
        src = m == 0 ? wq + o512 : m == 1 ? wk + o512 : m == 2 ? wv + o512 : wo + o512;
        dst = base + (size_t)m * 262144;
        K = 512; N = 512; tn = r & 15; tk = r >> 4;
    } else if (t < 2048) {                  // w1 (512x2048)
        int r = t - 1024;
        src = w1 + o1m; dst = base + 1048576;
        K = 512; N = 2048; tn = r & 63; tk = r >> 6;
    } else {                                // w2 (2048x512)
        int r = t - 2048;
        src = w2 + o1m; dst = base + 2097152;
        K = 2048; N = 512; tn = r & 15; tk = r >> 4;
    }
    __shared__ float tile[32][33];
    const int tx = threadIdx.x & 31, ty = threadIdx.x >> 5;
    const int n0 = tn * 32, k0 = tk * 32;
#pragma unroll
    for (int i = 0; i < 4; i++)
        tile[ty + i * 8][tx] = src[(size_t)(k0 + ty + i * 8) * N + n0 + tx];
    __syncthreads();
#pragma unroll
    for (int i = 0; i < 4; i++)
        dst[(size_t)(n0 + ty + i * 8) * K + k0 + tx] = f2bf(tile[tx][ty + i * 8]);
}

// ---------------- LayerNorm ----------------
DEV void ln_body(const float* xr, const float* g, const float* bb, u16* orow) {
    const int t = threadIdx.x;
    float v0 = xr[t], v1 = xr[t + 256];
    float s = v0 + v1, s2 = v0 * v0 + v1 * v1;
#pragma unroll
    for (int off = 32; off > 0; off >>= 1) {
        s  += __shfl_down(s,  off);
        s2 += __shfl_down(s2, off);
    }
    __shared__ float red[8];
    const int w = t >> 6, ln = t & 63;
    if (ln == 0) { red[w] = s; red[4 + w] = s2; }
    __syncthreads();
    s  = red[0] + red[1] + red[2] + red[3];
    s2 = red[4] + red[5] + red[6] + red[7];
    float mean = s * (1.f / 512.f);
    float var  = s2 * (1.f / 512.f) - mean * mean;
    float rstd = rsqrtf(var + 1e-5f);
    orow[t]       = f2bf((v0 - mean) * rstd * g[t]       + bb[t]);
    orow[t + 256] = f2bf((v1 - mean) * rstd * g[t + 256] + bb[t + 256]);
}

__global__ __launch_bounds__(256)
void ln_k(const float* __restrict__ x, const float* __restrict__ g,
          const float* __restrict__ bb, u16* __restrict__ o) {
    const int row = blockIdx.x;
    ln_body(x + (size_t)row * 512, g, bb, o + (size_t)row * 512);
}

__global__ __launch_bounds__(256)
void lnd_k(const float* __restrict__ x0, u16* __restrict__ o0,
           const float* __restrict__ x1, u16* __restrict__ o1,
           const float* __restrict__ g, const float* __restrict__ bb) {
    const int row = blockIdx.x;
    const float* x = blockIdx.y ? x1 : x0;
    u16* o = blockIdx.y ? o1 : o0;
    ln_body(x + (size_t)row * 512, g, bb, o + (size_t)row * 512);
}

// ---------------- GEMM: A (M,K) bf16 @ Bt (N,K) bf16 + bias -> out ----------------
// Grid: blockIdx.x = m-tile (FAST), blockIdx.y = n-tile (outer) — measured best (R9/R11).
// BK=32: linear LDS rows. BK=64: 128B rows, XOR swizzle both sides (rule #21).
// ffn1 stays <128,32> (R12 A/B: <64,64> neutral — BN=128 width already amortizes barriers).
// EPI 0: bf16 = acc+bias ; 1: bf16 relu ; 2: f32 = acc+bias+res
template<int BN, int BK, int EPI>
__global__ __launch_bounds__(256, 3)
void gemm_k(const u16* __restrict__ A, const u16* __restrict__ Bt,
            const float* __restrict__ bias, const float* __restrict__ res,
            void* __restrict__ outp, int M, int N, int K) {
    __shared__ u16 As[2][128 * BK];
    __shared__ u16 Bs[2][BN * BK];
    const int tid = threadIdx.x, w = tid >> 6, ln = tid & 63;
    const int m0 = blockIdx.x * 128, n0 = blockIdx.y * BN;
    const int wr = (w >> 1) * 64, wc = (w & 1) * (BN / 2);
    const int l15 = ln & 15, l4 = ln >> 4;
    constexpr int NI = BN / 32;

    f32x4 acc[4][NI];
#pragma unroll
    for (int mi = 0; mi < 4; mi++)
#pragma unroll
        for (int ni = 0; ni < NI; ni++) acc[mi][ni] = fzero();

    auto stage = [&](int buf, int k0) {
        if constexpr (BK == 32) {
#pragma unroll
            for (int i = 0; i < 2; i++) {               // A: 8 chunks of 16 rows
                int chunk = i * 4 + w;
                int r = chunk * 16 + (ln >> 2);
                async16(A + (size_t)(m0 + r) * K + k0 + (ln & 3) * 8, &As[buf][chunk * 512]);
            }
#pragma unroll
            for (int i = 0; i < BN / 64; i++) {
                int chunk = i * 4 + w;
                int r = chunk * 16 + (ln >> 2);
                async16(Bt + (size_t)(n0 + r) * K + k0 + (ln & 3) * 8, &Bs[buf][chunk * 512]);
            }
        } else {                                        // BK == 64, swizzled
            const int srow = ln >> 3;
            const int scol = ((ln & 7) ^ srow) * 8;
#pragma unroll
            for (int i = 0; i < 4; i++) {               // A: 16 chunks of 8 rows
                int chunk = i * 4 + w;
                int r = chunk * 8 + srow;
                async16(A + (size_t)(m0 + r) * K + k0 + scol, &As[buf][chunk * 512]);
            }
#pragma unroll
            for (int i = 0; i < BN / 32; i++) {         // B: BN/8 chunks of 8 rows
                int chunk = i * 4 + w;
                int r = chunk * 8 + srow;
                async16(Bt + (size_t)(n0 + r) * K + k0 + scol, &Bs[buf][chunk * 512]);
            }
        }
    };

    stage(0, 0);
    __syncthreads();
    const int nk = K / BK;
    for (int kt = 0; kt < nk; ++kt) {
        const int cur = kt & 1;
        if (kt + 1 < nk) stage(cur ^ 1, (kt + 1) * BK);
        if constexpr (BK == 32) {
            bf16x8 a[4], b[NI];
#pragma unroll
            for (int mi = 0; mi < 4; mi++)
                a[mi] = load8(&As[cur][(wr + mi * 16 + l15) * 32 + l4 * 8]);
#pragma unroll
            for (int ni = 0; ni < NI; ni++)
                b[ni] = load8(&Bs[cur][(wc + ni * 16 + l15) * 32 + l4 * 8]);
#pragma unroll
            for (int mi = 0; mi < 4; mi++)
#pragma unroll
                for (int ni = 0; ni < NI; ni++)
                    acc[mi][ni] = mfma16(a[mi], b[ni], acc[mi][ni]);
        } else {
            const int swl = (l15 & 7) << 4;
#pragma unroll
            for (int ks = 0; ks < 2; ks++) {
                bf16x8 a[4], b[NI];
#pragma unroll
                for (int mi = 0; mi < 4; mi++) {
                    const char* ba = (const char*)&As[cur][(wr + mi * 16 + l15) * 64];
                    a[mi] = load8((const u16*)(ba + ((ks * 64 + l4 * 16) ^ swl)));
                }
#pragma unroll
                for (int ni = 0; ni < NI; ni++) {
                    const char* bb2 = (const char*)&Bs[cur][(wc + ni * 16 + l15) * 64];
                    b[ni] = load8((const u16*)(bb2 + ((ks * 64 + l4 * 16) ^ swl)));
                }
#pragma unroll
                for (int mi = 0; mi < 4; mi++)
#pragma unroll
                    for (int ni = 0; ni < NI; ni++)
                        acc[mi][ni] = mfma16(a[mi], b[ni], acc[mi][ni]);
            }
        }
        __syncthreads();
    }

#pragma unroll
    for (int mi = 0; mi < 4; mi++)
#pragma unroll
        for (int ni = 0; ni < NI; ni++) {
            int row0 = m0 + wr + mi * 16 + l4 * 4;
            int col  = n0 + wc + ni * 16 + l15;
            float bv = bias[col];
#pragma unroll
            for (int j = 0; j < 4; j++) {
                float v = acc[mi][ni][j] + bv;
                size_t off = (size_t)(row0 + j) * N + col;
                if constexpr (EPI == 2) ((float*)outp)[off] = v + res[off];
                else if constexpr (EPI == 1) ((u16*)outp)[off] = f2bf(v > 0.f ? v : 0.f);
                else ((u16*)outp)[off] = f2bf(v);
            }
        }
}

// ---------------- merged QKV GEMM (N=1536), V written transposed ----------------
// grid (64, 12): m fast (R9 order)
__global__ __launch_bounds__(256, 3)
void gemm_qkv(const u16* __restrict__ A1, const u16* __restrict__ A2,
              const u16* __restrict__ Bt, const float* __restrict__ bias,
              u16* __restrict__ qkB, u16* __restrict__ vTp) {
    constexpr int K = 512;
    __shared__ u16 As[2][128 * 32];
    __shared__ u16 Bs[2][128 * 32];
    const int tid = threadIdx.x, w = tid >> 6, ln = tid & 63;
    const int m0 = blockIdx.x * 128, n0 = blockIdx.y * 128;
    const int wr = (w >> 1) * 64, wc = (w & 1) * 64;
    const int l15 = ln & 15, l4 = ln >> 4;
    const u16* A = (n0 >= 512) ? A2 : A1;

    f32x4 acc[4][4];
#pragma unroll
    for (int mi = 0; mi < 4; mi++)
#pragma unroll
        for (int ni = 0; ni < 4; ni++) acc[mi][ni] = fzero();

    auto stage = [&](int buf, int k0) {
#pragma unroll
        for (int i = 0; i < 2; i++) {
            int chunk = i * 4 + w;
            int r = chunk * 16 + (ln >> 2);
            async16(A + (size_t)(m0 + r) * K + k0 + (ln & 3) * 8, &As[buf][chunk * 512]);
            async16(Bt + (size_t)(n0 + r) * K + k0 + (ln & 3) * 8, &Bs[buf][chunk * 512]);
        }
    };

    stage(0, 0);
    __syncthreads();
    for (int kt = 0; kt < 16; ++kt) {
        const int cur = kt & 1;
        if (kt + 1 < 16) stage(cur ^ 1, (kt + 1) * 32);
        bf16x8 a[4], b[4];
#pragma unroll
        for (int mi = 0; mi < 4; mi++)
            a[mi] = load8(&As[cur][(wr + mi * 16 + l15) * 32 + l4 * 8]);
#pragma unroll
        for (int ni = 0; ni < 4; ni++)
            b[ni] = load8(&Bs[cur][(wc + ni * 16 + l15) * 32 + l4 * 8]);
#pragma unroll
        for (int mi = 0; mi < 4; mi++)
#pragma unroll
            for (int ni = 0; ni < 4; ni++)
                acc[mi][ni] = mfma16(a[mi], b[ni], acc[mi][ni]);
        __syncthreads();
    }

    if (n0 < 1024) {
        const float scale = (n0 < 512) ? QSCALE : 1.f;   // Q prescaled for exp2 softmax
#pragma unroll
        for (int mi = 0; mi < 4; mi++)
#pragma unroll
            for (int ni = 0; ni < 4; ni++) {
                int row0 = m0 + wr + mi * 16 + l4 * 4;
                int col  = n0 + wc + ni * 16 + l15;
                float bv = bias[col];
#pragma unroll
                for (int j = 0; j < 4; j++)
                    qkB[(size_t)(row0 + j) * 1024 + col] = f2bf((acc[mi][ni][j] + bv) * scale);
            }
    } else {
#pragma unroll
        for (int mi = 0; mi < 4; mi++)
#pragma unroll
            for (int ni = 0; ni < 4; ni++) {
                int row0 = m0 + wr + mi * 16 + l4 * 4;
                int col  = n0 + wc + ni * 16 + l15;
                float bv = bias[col];
                int c = col - 1024;
                int bh = (row0 >> 11) * 8 + (c >> 6);
                ushort4 pk;
                pk.x = f2bf(acc[mi][ni][0] + bv);
                pk.y = f2bf(acc[mi][ni][1] + bv);
                pk.z = f2bf(acc[mi][ni][2] + bv);
                pk.w = f2bf(acc[mi][ni][3] + bv);
                *(ushort4*)(vTp + (size_t)bh * 131072 + (size_t)(c & 63) * 2048 + (row0 & 2047)) = pk;
            }
    }
}

// ---------------- flash attention v6: swapped QK^T, exp2, perm-pack, setprio ----------
__global__ __launch_bounds__(256, 3)
void attn_k(const u16* __restrict__ qh, int qstr, const u16* __restrict__ kh, int kstr,
            const u16* __restrict__ vT, u16* __restrict__ o) {
    __shared__ u16 Kt[2][4096];   // [kk][hd] swizzled rows, 64 x 128B
    __shared__ u16 Vt[2][4096];   // [hd][kk] swizzled rows, 64 x 128B
    __shared__ u16 Pl[4][2048];   // per-wave [q][kk], 32 x 128B, swizzled rows
    const int tid = threadIdx.x, w = tid >> 6, ln = tid & 63;
    const int orig = blockIdx.y * 16 + blockIdx.x;   // nwg=512, cpx=64
    const int swz = (orig & 7) * 64 + (orig >> 3);
    const int bx = swz & 15, by = swz >> 4;
    const int b = by >> 3, h = by & 7;
    const int q0 = bx * 128;
    const size_t bS = (size_t)b * 2048;
    const int h64 = h * 64;
    const int l15 = ln & 15, l4 = ln >> 4;

    const int srow = ln >> 3;
    const int scol = ((ln & 7) ^ srow) * 8;

    const u16* qp = qh + (bS + q0 + w * 32 + l15) * qstr + h64;
    bf16x8 qa[2][2];
    qa[0][0] = load8(qp + l4 * 8);
    qa[0][1] = load8(qp + 32 + l4 * 8);
    qa[1][0] = load8(qp + 16 * qstr + l4 * 8);
    qa[1][1] = load8(qp + 16 * qstr + 32 + l4 * 8);

    const u16* kbase = kh + bS * kstr + h64;
    const u16* vbase = vT + (size_t)(b * 8 + h) * 131072;

    auto stage = [&](int buf, int sk) {
#pragma unroll
        for (int i = 0; i < 2; i++) {
            int chunk = i * 4 + w;
            int row = chunk * 8 + srow;
            async16(kbase + (size_t)(sk + row) * kstr + scol, &Kt[buf][chunk * 512]);
            async16(vbase + (size_t)row * 2048 + sk + scol, &Vt[buf][chunk * 512]);
        }
    };

    float l_acc[2];
    f32x4 oacc[2][4];
#pragma unroll
    for (int mf = 0; mf < 2; mf++) {
        l_acc[mf] = 0.f;
#pragma unroll
        for (int j = 0; j < 4; j++) oacc[mf][j] = fzero();
    }

    const int swl = (l15 & 7) << 4;

    stage(0, 0);
    for (int t = 0; t < 32; ++t) {
        const int cur = t & 1;
        __syncthreads();
        if (t < 31) stage(cur ^ 1, (t + 1) * 64);

        const char* KtC = (const char*)Kt[cur];
        const char* VtC = (const char*)Vt[cur];

        // S^T = mfma(K, Q): s[mf][ni] -> lane: q = mf*16+l15, kk = ni*16+l4*4+j
        f32x4 s[2][4];
        __builtin_amdgcn_s_setprio(1);
#pragma unroll
        for (int ni = 0; ni < 4; ni++) {
            const char* kr = KtC + (ni * 16 + l15) * 128;
            bf16x8 kb0 = load8((const u16*)(kr + ((l4 * 16) ^ swl)));
            bf16x8 kb1 = load8((const u16*)(kr + ((64 + l4 * 16) ^ swl)));
            s[0][ni] = mfma16(kb0, qa[0][0], fzero());
            s[0][ni] = mfma16(kb1, qa[0][1], s[0][ni]);
            s[1][ni] = mfma16(kb0, qa[1][0], fzero());
            s[1][ni] = mfma16(kb1, qa[1][1], s[1][ni]);
        }
        __builtin_amdgcn_s_setprio(0);

        // P = 2^s (Q prescaled by 0.125*log2e); truncate-pack via v_perm; raw l-sum
        char* Pw = (char*)Pl[w];
#pragma unroll
        for (int mf = 0; mf < 2; mf++) {
            const int qrow = mf * 16 + l15;
            char* Pr = Pw + qrow * 128;
            const int qsw = (qrow & 7) << 4;
#pragma unroll
            for (int jj = 0; jj < 2; jj++)
#pragma unroll
                for (int ni = 0; ni < 4; ni++) {
                    const int boff = ni * 32 + l4 * 8;
                    float p0 = EXP2(s[mf][ni][jj * 2]);
                    float p1 = EXP2(s[mf][ni][jj * 2 + 1]);
                    union { float f; unsigned u; } c0, c1;
                    c0.f = p0; c1.f = p1;
                    l_acc[mf] += p0 + p1;
                    *(unsigned*)(Pr + ((boff + jj * 4) ^ qsw)) =
                        __builtin_amdgcn_perm(c1.u, c0.u, 0x07060302u);
                }
        }

        // PV: oacc[mf][hd4] += P(32x64) @ V^T rows
        bf16x8 pa[2][2];
#pragma unroll
        for (int mf = 0; mf < 2; mf++) {
            pa[mf][0] = load8((const u16*)(Pw + (mf * 16 + l15) * 128 + ((l4 * 16) ^ swl)));
            pa[mf][1] = load8((const u16*)(Pw + (mf * 16 + l15) * 128 + ((64 + l4 * 16) ^ swl)));
        }
        __builtin_amdgcn_s_setprio(1);
#pragma unroll
        for (int hd4 = 0; hd4 < 4; hd4++) {
            const char* vr = VtC + (hd4 * 16 + l15) * 128;
            bf16x8 vb0 = load8((const u16*)(vr + ((l4 * 16) ^ swl)));
            bf16x8 vb1 = load8((const u16*)(vr + ((64 + l4 * 16) ^ swl)));
            oacc[0][hd4] = mfma16(pa[0][0], vb0, oacc[0][hd4]);
            oacc[0][hd4] = mfma16(pa[0][1], vb1, oacc[0][hd4]);
            oacc[1][hd4] = mfma16(pa[1][0], vb0, oacc[1][hd4]);
            oacc[1][hd4] = mfma16(pa[1][1], vb1, oacc[1][hd4]);
        }
        __builtin_amdgcn_s_setprio(0);
    }

    // reduce l across the 4 l4 groups, redistribute to O-write layout
    float rlj[2][4];
#pragma unroll
    for (int mf = 0; mf < 2; mf++) {
        l_acc[mf] += __shfl_xor(l_acc[mf], 16);
        l_acc[mf] += __shfl_xor(l_acc[mf], 32);
        float inv = 1.f / l_acc[mf];
#pragma unroll
        for (int j = 0; j < 4; j++)
            rlj[mf][j] = __shfl(inv, (ln & 48) | (l4 * 4 + j));
    }

#pragma unroll
    for (int mf = 0; mf < 2; mf++)
#pragma unroll
        for (int hd4 = 0; hd4 < 4; hd4++)
#pragma unroll
            for (int j = 0; j < 4; j++) {
                float v = oacc[mf][hd4][j] * rlj[mf][j];
                size_t row = bS + q0 + w * 32 + mf * 16 + l4 * 4 + j;
                o[row * 512 + h64 + hd4 * 16 + l15] = f2bf(v);
            }
}

// ---------------- driver ----------------
extern "C" void kernel_launch(void* const* d_in, const int* in_sizes, int n_in,
                              void* d_out, int out_size, void* d_ws, size_t ws_size,
                              hipStream_t stream) {
    const float* q    = (const float*)d_in[0];
    const float* ln1g = (const float*)d_in[1];
    const float* ln1b = (const float*)d_in[2];
    const float* wq   = (const float*)d_in[3];
    const float* bq   = (const float*)d_in[4];
    const float* wk   = (const float*)d_in[5];
    const float* bk   = (const float*)d_in[6];
    const float* wv   = (const float*)d_in[7];
    const float* bv   = (const float*)d_in[8];
    const float* wo   = (const float*)d_in[9];
    const float* bo   = (const float*)d_in[10];
    const float* ln2g = (const float*)d_in[11];
    const float* ln2b = (const float*)d_in[12];
    const float* w1   = (const float*)d_in[13];
    const float* b1   = (const float*)d_in[14];
    const float* w2   = (const float*)d_in[15];
    const float* b2   = (const float*)d_in[16];

    char* ws = (char*)d_ws;
    size_t off = 0;
    auto take = [&](size_t bytes) -> char* {
        char* p = ws + off; off += (bytes + 255) & ~(size_t)255; return p;
    };
    u16*   wT   = (u16*)take(6291456ull * 2);    // transposed bf16 weights
    float* bqkv = (float*)take(2 * 1536 * 4);    // per-layer concat(bq,bk,bv)
    float* xA   = (float*)take(4194304ull * 4);  // f32 residual stream A
    float* xB   = (float*)take(4194304ull * 4);  // f32 residual stream B
    u16*   qn   = (u16*)take(4194304ull * 2);    // LN(x); reused as attn output
    u16*   kn   = (u16*)take(4194304ull * 2);    // LN(q); reused as LN2 output
    u16*   qkB  = (u16*)take(8388608ull * 2);    // merged Q|K proj (8192 x 1024)
    u16*   hbuf = (u16*)take(16777216ull * 2);   // FFN hidden bf16
    u16*   vTb  = hbuf;                          // alias: vT used only pre-FFN
    (void)ws_size; (void)in_sizes; (void)n_in; (void)out_size;

    prep<<<6156, 256, 0, stream>>>(wq, wk, wv, wo, w1, w2, bq, bk, bv, wT, bqkv);

    const float* xcur = q;
    for (int l = 0; l < 2; l++) {
        u16* base = wT + (size_t)l * 3145728;
        if (l == 0) {
            ln_k<<<8192, 256, 0, stream>>>(q, ln1g, ln1b, qn);       // x==q: one LN
        } else {
            lnd_k<<<dim3(8192, 2), 256, 0, stream>>>(xcur, qn, q, kn,
                                                     ln1g + 512, ln1b + 512);
        }
        const u16* A2 = (l == 0) ? qn : kn;
        gemm_qkv<<<dim3(64, 12), 256, 0, stream>>>(qn, A2, base, bqkv + l * 1536, qkB, vTb);
        attn_k<<<dim3(16, 32), 256, 0, stream>>>(qkB, 1024, qkB + 512, 1024, vTb, qn);
        gemm_k<64, 64, 2><<<dim3(64, 8), 256, 0, stream>>>(qn, base + 786432, bo + l * 512, xcur, xA, 8192, 512, 512);
        ln_k<<<8192, 256, 0, stream>>>(xA, ln2g + l * 512, ln2b + l * 512, kn);
        gemm_k<128, 32, 1><<<dim3(64, 16), 256, 0, stream>>>(kn, base + 1048576, b1 + l * 2048, nullptr, hbuf, 8192, 2048, 512);
        float* xout = (l == 1) ? (float*)d_out : xB;
        gemm_k<64, 64, 2><<<dim3(64, 8), 256, 0, stream>>>(hbuf, base + 2097152, b2 + l * 512, xA, xout, 8192, 512, 2048);
        xcur = xout;
    }
}